// Round 2
// baseline (5527.311 us; speedup 1.0000x reference)
//
#include <hip/hip_runtime.h>

#define NROWS 10000
#define DDEG  32
#define FDIM  512
#define MP    10112   // 79 * 128
#define MT    79
#define GN    2048    // 4*F

typedef unsigned short u16;
typedef __bf16 bf16x8 __attribute__((ext_vector_type(8)));
typedef float  float4v __attribute__((ext_vector_type(4)));

typedef __attribute__((address_space(3))) uint32_t lds_u32;
typedef __attribute__((address_space(1))) const uint32_t gbl_u32;

__device__ __forceinline__ void load_lds16(const void* g, void* l) {
    __builtin_amdgcn_global_load_lds((gbl_u32*)g, (lds_u32*)l, 16, 0, 0);
}

__device__ __forceinline__ u16 f2b(float f) {
    union { unsigned u; float f; } v; v.f = f;
    unsigned u = v.u;
    unsigned r = (u + 0x7fffu + ((u >> 16) & 1u)) >> 16;
    return (u16)r;
}
__device__ __forceinline__ float sigm(float x) { return 1.f / (1.f + __expf(-x)); }

__device__ __forceinline__ float4v mfma16(bf16x8 a, bf16x8 b, float4v c) {
    return __builtin_amdgcn_mfma_f32_16x16x32_bf16(a, b, c, 0, 0, 0);
}

// NT GEMM core: A [.,512] bf16 row-major, B [.,512] bf16 row-major (= B^T of the math),
// 128x128 block tile, 4 waves of 64x64, BK=32.
__device__ __forceinline__ void gemm_core(const u16* __restrict__ A, const u16* __restrict__ B,
                                          int K, int mB, int nB,
                                          u16* Asm, u16* Bsm, float4v acc[4][4])
{
    const int tid  = threadIdx.x;
    const int lane = tid & 63, wid = tid >> 6;
    const int wm = (wid >> 1) << 6, wn = (wid & 1) << 6;
    const int l15 = lane & 15, quad = lane >> 4;
    const int ktn = K >> 5;
    for (int kt = 0; kt < ktn; ++kt) {
        __syncthreads();
        const int kof = kt << 5;
#pragma unroll
        for (int it = 0; it < 2; ++it) {
            int c   = (it << 8) + (wid << 6) + lane;   // chunk 0..511: row=c>>2, kchunk=c&3
            int row = c >> 2, kc = c & 3;
            int ldsbase = ((it << 8) + (wid << 6)) << 3;  // u16 elements, wave-uniform
            load_lds16(A + (size_t)(mB + row) * 512 + kof + (kc << 3), &Asm[ldsbase]);
            load_lds16(B + (size_t)(nB + row) * 512 + kof + (kc << 3), &Bsm[ldsbase]);
        }
        __syncthreads();
        bf16x8 af[4], bfr[4];
#pragma unroll
        for (int i = 0; i < 4; ++i) {
            af[i]  = *(const bf16x8*)(void*)&Asm[(wm + (i << 4) + l15) * 32 + quad * 8];
            bfr[i] = *(const bf16x8*)(void*)&Bsm[(wn + (i << 4) + l15) * 32 + quad * 8];
        }
#pragma unroll
        for (int mi = 0; mi < 4; ++mi)
#pragma unroll
            for (int ni = 0; ni < 4; ++ni)
                acc[mi][ni] = mfma16(af[mi], bfr[ni], acc[mi][ni]);
    }
}

// C(fp32) = A * B^T + bias
__global__ void __launch_bounds__(256)
gemm_biasF(const u16* __restrict__ A, const u16* __restrict__ B,
           const float* __restrict__ bias, float* __restrict__ C, int ldc)
{
    __shared__ u16 Asm[128 * 32], Bsm[128 * 32];
    const int mB = blockIdx.x << 7, nB = blockIdx.y << 7;
    const int tid = threadIdx.x, lane = tid & 63, wid = tid >> 6;
    const int wm = (wid >> 1) << 6, wn = (wid & 1) << 6;
    const int l15 = lane & 15, quad = lane >> 4;
    float4v acc[4][4];
    float4v z = {0.f, 0.f, 0.f, 0.f};
#pragma unroll
    for (int i = 0; i < 4; ++i)
#pragma unroll
        for (int j = 0; j < 4; ++j) acc[i][j] = z;
    gemm_core(A, B, 512, mB, nB, Asm, Bsm, acc);
#pragma unroll
    for (int mi = 0; mi < 4; ++mi) {
        int m0 = mB + wm + (mi << 4) + (quad << 2);
#pragma unroll
        for (int ni = 0; ni < 4; ++ni) {
            int n = nB + wn + (ni << 4) + l15;
            float bb = bias[n];
#pragma unroll
            for (int r = 0; r < 4; ++r) {
                int m = m0 + r;
                if (m < NROWS) C[(size_t)m * ldc + n] = acc[mi][ni][r] + bb;
            }
        }
    }
}

// hs(bf16) = x*WselfT^T + h1*WneighT^T + b   (512 cols)
__global__ void __launch_bounds__(256)
gemm_sage(const u16* __restrict__ A1, const u16* __restrict__ B1,
          const u16* __restrict__ A2, const u16* __restrict__ B2,
          const float* __restrict__ bias, u16* __restrict__ C)
{
    __shared__ u16 Asm[128 * 32], Bsm[128 * 32];
    const int mB = blockIdx.x << 7, nB = blockIdx.y << 7;
    const int tid = threadIdx.x, lane = tid & 63, wid = tid >> 6;
    const int wm = (wid >> 1) << 6, wn = (wid & 1) << 6;
    const int l15 = lane & 15, quad = lane >> 4;
    float4v acc[4][4];
    float4v z = {0.f, 0.f, 0.f, 0.f};
#pragma unroll
    for (int i = 0; i < 4; ++i)
#pragma unroll
        for (int j = 0; j < 4; ++j) acc[i][j] = z;
    gemm_core(A1, B1, 512, mB, nB, Asm, Bsm, acc);
    gemm_core(A2, B2, 512, mB, nB, Asm, Bsm, acc);
#pragma unroll
    for (int mi = 0; mi < 4; ++mi) {
        int m0 = mB + wm + (mi << 4) + (quad << 2);
#pragma unroll
        for (int ni = 0; ni < 4; ++ni) {
            int n = nB + wn + (ni << 4) + l15;
            float bb = bias[n];
#pragma unroll
            for (int r = 0; r < 4; ++r) {
                int m = m0 + r;
                if (m < NROWS) C[(size_t)m * 512 + n] = f2b(acc[mi][ni][r] + bb);
            }
        }
    }
}

// One LSTM step: g = gateX[src[:,t]] (fp32, permuted cols) + Hprev*Whh_p^T, per-lane cell update.
// Permuted col p = grp*64 + gate*16 + u  <->  source row gate*512 + grp*16 + u.
// C/D layout: col = lane&15, row = quad*4 + reg  ->  4 gates of one unit live in one lane.
__global__ void __launch_bounds__(256)
gemm_step(const u16* __restrict__ Hprev, const u16* __restrict__ Bw, int K,
          const float* __restrict__ gateX, const int* __restrict__ src, int t,
          float* __restrict__ Cst, u16* __restrict__ Hnew, float* __restrict__ Hout)
{
    __shared__ u16 Asm[128 * 32], Bsm[128 * 32];
    const int mB = blockIdx.x << 7, nB = blockIdx.y << 7;
    const int tid = threadIdx.x, lane = tid & 63, wid = tid >> 6;
    const int wm = (wid >> 1) << 6, wn = (wid & 1) << 6;
    const int l15 = lane & 15, quad = lane >> 4;
    const int slab = nB + wn;
    float4v acc[4][4];
    float4v z = {0.f, 0.f, 0.f, 0.f};
#pragma unroll
    for (int i = 0; i < 4; ++i)
#pragma unroll
        for (int j = 0; j < 4; ++j) acc[i][j] = z;
    // init accumulators from gathered fp32 input-side preactivations (+both biases)
#pragma unroll
    for (int mi = 0; mi < 4; ++mi) {
        int m0 = mB + wm + (mi << 4) + (quad << 2);
#pragma unroll
        for (int r = 0; r < 4; ++r) {
            int m = m0 + r;
            if (m < NROWS) {
                int s = src[m * DDEG + t];
                const float* g = gateX + (size_t)s * GN + slab + l15;
                acc[mi][0][r] = g[0];
                acc[mi][1][r] = g[16];
                acc[mi][2][r] = g[32];
                acc[mi][3][r] = g[48];
            }
        }
    }
    gemm_core(Hprev, Bw, K, mB, nB, Asm, Bsm, acc);
    const int unit = ((slab >> 6) << 4) + l15;
#pragma unroll
    for (int mi = 0; mi < 4; ++mi) {
        int m0 = mB + wm + (mi << 4) + (quad << 2);
#pragma unroll
        for (int r = 0; r < 4; ++r) {
            int m = m0 + r;
            if (m < NROWS) {
                float gi = acc[mi][0][r], gf = acc[mi][1][r];
                float gg = acc[mi][2][r], go = acc[mi][3][r];
                size_t ix = (size_t)m * FDIM + unit;
                float cprev = K ? Cst[ix] : 0.f;        // t==0: zero initial state, skip read
                float cn = sigm(gf) * cprev + sigm(gi) * tanhf(gg);
                Cst[ix] = cn;
                float hv = sigm(go) * tanhf(cn);
                Hnew[ix] = f2b(hv);
                if (Hout) Hout[ix] = hv;
            }
        }
    }
}

// Permute + fp32->bf16 LSTM weights: perm row p = grp*64 + gate*16 + u <- src row gate*512+grp*16+u
__global__ void prep_lstm(const float* __restrict__ Wih, const float* __restrict__ Whh,
                          const float* __restrict__ bih, const float* __restrict__ bhh,
                          u16* __restrict__ Wih_p, u16* __restrict__ Whh_p,
                          float* __restrict__ bias_p)
{
    int idx = blockIdx.x * 256 + threadIdx.x;   // 2048*512
    int p = idx >> 9, k = idx & 511;
    int gate = (p >> 4) & 3, grp = p >> 6, u = p & 15;
    int srow = (gate << 9) + (grp << 4) + u;
    int sidx = (srow << 9) + k;
    Wih_p[idx] = f2b(Wih[sidx]);
    Whh_p[idx] = f2b(Whh[sidx]);
    if (k == 0) bias_p[p] = bih[srow] + bhh[srow];
}

// Transpose + convert W_self/W_neigh; pad-convert x to bf16.
__global__ void prep_misc(const float* __restrict__ Wself, const float* __restrict__ Wneigh,
                          const float* __restrict__ x,
                          u16* __restrict__ WselfT, u16* __restrict__ WneighT,
                          u16* __restrict__ xp)
{
    int idx = blockIdx.x * 256 + threadIdx.x;   // MP*512
    if (idx < 512 * 512) {
        int n = idx >> 9, k = idx & 511;
        WselfT[idx]  = f2b(Wself[(k << 9) + n]);
        WneighT[idx] = f2b(Wneigh[(k << 9) + n]);
    }
    xp[idx] = (idx < NROWS * 512) ? f2b(x[idx]) : (u16)0;
}

extern "C" void kernel_launch(void* const* d_in, const int* in_sizes, int n_in,
                              void* d_out, int out_size, void* d_ws, size_t ws_size,
                              hipStream_t stream) {
    (void)in_sizes; (void)n_in; (void)out_size; (void)ws_size;
    const float* x     = (const float*)d_in[0];
    const int*   src   = (const int*)d_in[1];
    const float* Wih1  = (const float*)d_in[2];
    const float* Whh1  = (const float*)d_in[3];
    const float* bih1  = (const float*)d_in[4];
    const float* bhh1  = (const float*)d_in[5];
    const float* Wself = (const float*)d_in[6];
    const float* Wneigh= (const float*)d_in[7];
    const float* bvec  = (const float*)d_in[8];
    const float* Wih2  = (const float*)d_in[9];
    const float* Whh2  = (const float*)d_in[10];
    const float* bih2  = (const float*)d_in[11];
    const float* bhh2  = (const float*)d_in[12];
    float* out = (float*)d_out;

    char* w = (char*)d_ws;
    auto alloc = [&](size_t bytes) { char* p = w; w += (bytes + 255) & ~(size_t)255; return p; };
    u16*   xp     = (u16*)  alloc((size_t)MP * 512 * 2);
    u16*   ha     = (u16*)  alloc((size_t)MP * 512 * 2);
    u16*   hb     = (u16*)  alloc((size_t)MP * 512 * 2);
    float* cst    = (float*)alloc((size_t)NROWS * 512 * 4);
    float* gateX  = (float*)alloc((size_t)NROWS * GN * 4);
    u16*   Wih1p  = (u16*)  alloc((size_t)GN * 512 * 2);
    u16*   Whh1p  = (u16*)  alloc((size_t)GN * 512 * 2);
    u16*   Wih2p  = (u16*)  alloc((size_t)GN * 512 * 2);
    u16*   Whh2p  = (u16*)  alloc((size_t)GN * 512 * 2);
    u16*   WselfT = (u16*)  alloc((size_t)512 * 512 * 2);
    u16*   WneighT= (u16*)  alloc((size_t)512 * 512 * 2);
    float* bias1  = (float*)alloc(GN * 4);
    float* bias2  = (float*)alloc(GN * 4);
    u16*   hs     = (u16*)cst;   // aliases cst: live only gemm_sage -> gemm_biasF(stage2)

    dim3 blk(256);
    prep_lstm<<<4096, blk, 0, stream>>>(Wih1, Whh1, bih1, bhh1, Wih1p, Whh1p, bias1);
    prep_lstm<<<4096, blk, 0, stream>>>(Wih2, Whh2, bih2, bhh2, Wih2p, Whh2p, bias2);
    prep_misc<<<20224, blk, 0, stream>>>(Wself, Wneigh, x, WselfT, WneighT, xp);

    // Stage 1
    gemm_biasF<<<dim3(MT, 16), blk, 0, stream>>>(xp, Wih1p, bias1, gateX, GN);
    u16 *hp = ha, *hn = hb;
    for (int t = 0; t < DDEG; ++t) {
        gemm_step<<<dim3(MT, 16), blk, 0, stream>>>(hp, Whh1p, t ? 512 : 0, gateX, src, t,
                                                    cst, hn, nullptr);
        u16* tmp = hp; hp = hn; hn = tmp;
    }
    // SAGE combine: hs = x@Wself + h1@Wneigh + b   (hs aliases cst; stage-1 c is dead)
    gemm_sage<<<dim3(MT, 4), blk, 0, stream>>>(xp, WselfT, hp, WneighT, bvec, hs);
    // Stage 2 (gemm_biasF consumes hs before any step overwrites the cst region)
    gemm_biasF<<<dim3(MT, 16), blk, 0, stream>>>(hs, Wih2p, bias2, gateX, GN);
    hp = ha; hn = hb;
    for (int t = 0; t < DDEG; ++t) {
        gemm_step<<<dim3(MT, 16), blk, 0, stream>>>(hp, Whh2p, t ? 512 : 0, gateX, src, t,
                                                    cst, hn, (t == DDEG - 1) ? out : nullptr);
        u16* tmp = hp; hp = hn; hn = tmp;
    }
}

// Round 3
// 2697.983 us; speedup vs baseline: 2.0487x; 2.0487x over previous
//
#include <hip/hip_runtime.h>

#define NROWS 10000
#define DDEG  32
#define FDIM  512
#define MP    10112   // 79*128, padded M for the tiled aux GEMMs
#define MT    79
#define GN    2048    // 4*F
#define MTILE 48      // nodes per scan block
#define NBLK  209     // ceil(10000/48)

typedef unsigned short u16;
typedef __bf16 bf16x8 __attribute__((ext_vector_type(8)));
typedef float  float4v __attribute__((ext_vector_type(4)));
typedef _Float16 half4 __attribute__((ext_vector_type(4)));

typedef __attribute__((address_space(3))) uint32_t lds_u32;
typedef __attribute__((address_space(1))) const uint32_t gbl_u32;

__device__ __forceinline__ void load_lds16(const void* g, void* l) {
    __builtin_amdgcn_global_load_lds((gbl_u32*)g, (lds_u32*)l, 16, 0, 0);
}

__device__ __forceinline__ u16 f2b(float f) {
    union { unsigned u; float f; } v; v.f = f;
    unsigned u = v.u;
    return (u16)((u + 0x7fffu + ((u >> 16) & 1u)) >> 16);
}
__device__ __forceinline__ float sigm(float x) { return 1.f / (1.f + __expf(-x)); }
__device__ __forceinline__ float tanh_fast(float x) {
    float e = __expf(2.f * x);           // inf for large x, 0 for very negative -> +-1 exact
    return 1.f - 2.f / (e + 1.f);
}

__device__ __forceinline__ float4v mfma16(bf16x8 a, bf16x8 b, float4v c) {
    return __builtin_amdgcn_mfma_f32_16x16x32_bf16(a, b, c, 0, 0, 0);
}

// ---------------- aux NT GEMM core (m97-style), unchanged from R2 ----------------
__device__ __forceinline__ void gemm_core(const u16* __restrict__ A, const u16* __restrict__ B,
                                          int K, int mB, int nB,
                                          u16* Asm, u16* Bsm, float4v acc[4][4])
{
    const int tid  = threadIdx.x;
    const int lane = tid & 63, wid = tid >> 6;
    const int wm = (wid >> 1) << 6, wn = (wid & 1) << 6;
    const int l15 = lane & 15, quad = lane >> 4;
    const int ktn = K >> 5;
    for (int kt = 0; kt < ktn; ++kt) {
        __syncthreads();
        const int kof = kt << 5;
#pragma unroll
        for (int it = 0; it < 2; ++it) {
            int c   = (it << 8) + (wid << 6) + lane;
            int row = c >> 2, kc = c & 3;
            int ldsbase = ((it << 8) + (wid << 6)) << 3;
            load_lds16(A + (size_t)(mB + row) * 512 + kof + (kc << 3), &Asm[ldsbase]);
            load_lds16(B + (size_t)(nB + row) * 512 + kof + (kc << 3), &Bsm[ldsbase]);
        }
        __syncthreads();
        bf16x8 af[4], bfr[4];
#pragma unroll
        for (int i = 0; i < 4; ++i) {
            af[i]  = *(const bf16x8*)(void*)&Asm[(wm + (i << 4) + l15) * 32 + quad * 8];
            bfr[i] = *(const bf16x8*)(void*)&Bsm[(wn + (i << 4) + l15) * 32 + quad * 8];
        }
#pragma unroll
        for (int mi = 0; mi < 4; ++mi)
#pragma unroll
            for (int ni = 0; ni < 4; ++ni)
                acc[mi][ni] = mfma16(af[mi], bfr[ni], acc[mi][ni]);
    }
}

// gateX(fp16, gate-minor [m][unit][4]) = A * Wih_p^T + biasv. B rows pre-permuted so
// n-tile ni == gate, l15 == unit-in-group -> one coalesced half4 store per cell.
__global__ void __launch_bounds__(256)
gemm_gatex(const u16* __restrict__ A, const u16* __restrict__ B,
           const float4v* __restrict__ biasv, half4* __restrict__ gX)
{
    __shared__ u16 Asm[128 * 32], Bsm[128 * 32];
    const int mB = blockIdx.x << 7, nB = blockIdx.y << 7;
    const int tid = threadIdx.x, lane = tid & 63, wid = tid >> 6;
    const int wm = (wid >> 1) << 6, wn = (wid & 1) << 6;
    const int l15 = lane & 15, quad = lane >> 4;
    float4v acc[4][4];
    float4v z = {0.f, 0.f, 0.f, 0.f};
#pragma unroll
    for (int i = 0; i < 4; ++i)
#pragma unroll
        for (int j = 0; j < 4; ++j) acc[i][j] = z;
    gemm_core(A, B, 512, mB, nB, Asm, Bsm, acc);
    const int slab = nB + wn;
    const int unit = ((slab >> 6) << 4) + l15;   // same for all cells of this thread
    float4v b4 = biasv[unit];
#pragma unroll
    for (int mi = 0; mi < 4; ++mi) {
        int m0 = mB + wm + (mi << 4) + (quad << 2);
#pragma unroll
        for (int r = 0; r < 4; ++r) {
            int m = m0 + r;
            if (m < NROWS) {
                half4 o;
                o[0] = (_Float16)(acc[mi][0][r] + b4[0]);
                o[1] = (_Float16)(acc[mi][1][r] + b4[1]);
                o[2] = (_Float16)(acc[mi][2][r] + b4[2]);
                o[3] = (_Float16)(acc[mi][3][r] + b4[3]);
                gX[(size_t)m * 512 + unit] = o;
            }
        }
    }
}

// hs(bf16) = x*WselfT^T + h1*WneighT^T + b
__global__ void __launch_bounds__(256)
gemm_sage(const u16* __restrict__ A1, const u16* __restrict__ B1,
          const u16* __restrict__ A2, const u16* __restrict__ B2,
          const float* __restrict__ bias, u16* __restrict__ C)
{
    __shared__ u16 Asm[128 * 32], Bsm[128 * 32];
    const int mB = blockIdx.x << 7, nB = blockIdx.y << 7;
    const int tid = threadIdx.x, lane = tid & 63, wid = tid >> 6;
    const int wm = (wid >> 1) << 6, wn = (wid & 1) << 6;
    const int l15 = lane & 15, quad = lane >> 4;
    float4v acc[4][4];
    float4v z = {0.f, 0.f, 0.f, 0.f};
#pragma unroll
    for (int i = 0; i < 4; ++i)
#pragma unroll
        for (int j = 0; j < 4; ++j) acc[i][j] = z;
    gemm_core(A1, B1, 512, mB, nB, Asm, Bsm, acc);
    gemm_core(A2, B2, 512, mB, nB, Asm, Bsm, acc);
#pragma unroll
    for (int mi = 0; mi < 4; ++mi) {
        int m0 = mB + wm + (mi << 4) + (quad << 2);
#pragma unroll
        for (int ni = 0; ni < 4; ++ni) {
            int n = nB + wn + (ni << 4) + l15;
            float bb = bias[n];
#pragma unroll
            for (int r = 0; r < 4; ++r) {
                int m = m0 + r;
                if (m < NROWS) C[(size_t)m * 512 + n] = f2b(acc[mi][ni][r] + bb);
            }
        }
    }
}

// ---------------- fused 32-step LSTM scan ----------------
// Block owns MTILE=48 nodes; 8 waves, wave w owns permuted gate-cols [w*256,(w+1)*256)
// as 4 passes of one 64-col group (grp = w*4+p = 16 units x 4 gates).
// h: LDS double-buffer (bf16). c: VGPRs. Whh: fragment-major global (Bf), direct b128 loads.
// gateX gather (fp16) issued at pass start, consumed in epilogue (latency hidden by K-loop).
__global__ void __launch_bounds__(512, 2)
lstm_scan(const u16* __restrict__ Bf, const half4* __restrict__ gX,
          const int* __restrict__ src, u16* __restrict__ hf_bf16, float* __restrict__ out_f32)
{
    __shared__ u16 hbuf[2][MTILE][520];
    __shared__ int srcl[MTILE * DDEG];
    const int tid = threadIdx.x;
    const int w = tid >> 6, lane = tid & 63;
    const int l15 = lane & 15, quad = lane >> 4;
    const int m0 = blockIdx.x * MTILE;

    // zero h buffer 0
    {
        uint32_t* hz = (uint32_t*)&hbuf[0][0][0];
        for (int i = tid; i < MTILE * 520 / 2; i += 512) hz[i] = 0u;
    }
    // stage src rows for this block's nodes ([node][DDEG] is contiguous)
    for (int i = tid; i < MTILE * DDEG; i += 512) {
        int g = m0 * DDEG + i;
        srcl[i] = (g < NROWS * DDEG) ? src[g] : 0;
    }
    __syncthreads();

    float cst[4][12];
#pragma unroll
    for (int p = 0; p < 4; ++p)
#pragma unroll
        for (int i = 0; i < 12; ++i) cst[p][i] = 0.f;

    for (int t = 0; t < DDEG; ++t) {
        const u16(*hc)[520] = hbuf[t & 1];
        u16(*hn)[520] = hbuf[(t + 1) & 1];
#pragma unroll
        for (int p = 0; p < 4; ++p) {
            const int grp = (w << 2) + p;
            const int unit = (grp << 4) + l15;
            // issue gathers (consumed only in epilogue)
            half4 gv[12];
#pragma unroll
            for (int mi = 0; mi < 3; ++mi)
#pragma unroll
                for (int r = 0; r < 4; ++r) {
                    int ml = (mi << 4) + (quad << 2) + r;
                    int s = srcl[ml * DDEG + t];
                    gv[mi * 4 + r] = gX[(size_t)s * 512 + unit];
                }
            float4v acc[3][4];
            float4v z = {0.f, 0.f, 0.f, 0.f};
#pragma unroll
            for (int mi = 0; mi < 3; ++mi)
#pragma unroll
                for (int g = 0; g < 4; ++g) acc[mi][g] = z;
            // K loop over 512 (16 kt of 32)
#pragma unroll 4
            for (int kt = 0; kt < 16; ++kt) {
                bf16x8 af[3], bfr[4];
#pragma unroll
                for (int mi = 0; mi < 3; ++mi)
                    af[mi] = *(const bf16x8*)(void*)&hc[(mi << 4) + l15][(kt << 5) + (quad << 3)];
                const u16* bp = Bf + (((grp << 4) + kt) << 11) + (lane << 3);
#pragma unroll
                for (int s_ = 0; s_ < 4; ++s_)
                    bfr[s_] = *(const bf16x8*)(void*)(bp + (s_ << 9));
#pragma unroll
                for (int mi = 0; mi < 3; ++mi)
#pragma unroll
                    for (int g = 0; g < 4; ++g)
                        acc[mi][g] = mfma16(af[mi], bfr[g], acc[mi][g]);
            }
            // cell update
#pragma unroll
            for (int mi = 0; mi < 3; ++mi)
#pragma unroll
                for (int r = 0; r < 4; ++r) {
                    int idx = mi * 4 + r;
                    int ml = (mi << 4) + (quad << 2) + r;
                    float gi = acc[mi][0][r] + (float)gv[idx][0];
                    float gf = acc[mi][1][r] + (float)gv[idx][1];
                    float gg = acc[mi][2][r] + (float)gv[idx][2];
                    float go = acc[mi][3][r] + (float)gv[idx][3];
                    float cn = sigm(gf) * cst[p][idx] + sigm(gi) * tanh_fast(gg);
                    cst[p][idx] = cn;
                    float hv = sigm(go) * tanh_fast(cn);
                    hn[ml][unit] = f2b(hv);
                    if (t == DDEG - 1) {
                        int m = m0 + ml;
                        if (m < NROWS) {
                            if (hf_bf16) hf_bf16[(size_t)m * 512 + unit] = f2b(hv);
                            if (out_f32) out_f32[(size_t)m * 512 + unit] = hv;
                        }
                    }
                }
        }
        __syncthreads();
    }
}

// ---------------- prep kernels ----------------
// Wih permuted rows (p = grp*64+gate*16+u <- srow = gate*512+grp*16+u), bias gate-minor.
__global__ void prep_lstm_w(const float* __restrict__ Wih,
                            const float* __restrict__ bih, const float* __restrict__ bhh,
                            u16* __restrict__ Wih_p, float* __restrict__ biasv)
{
    int idx = blockIdx.x * 256 + threadIdx.x;   // 2048*512
    int p = idx >> 9, k = idx & 511;
    int gate = (p >> 4) & 3, grp = p >> 6, u = p & 15;
    int srow = (gate << 9) + (grp << 4) + u;
    Wih_p[idx] = f2b(Wih[(srow << 9) + k]);
    if (k == 0) {
        int unit = (grp << 4) + u;
        biasv[(unit << 2) + gate] = bih[srow] + bhh[srow];
    }
}

// Whh -> fragment-major Bf: element (grp,kt,s,lane,j) = Whh[s*512+grp*16+(lane&15)][kt*32+(lane>>4)*8+j]
__global__ void prep_whh_frag(const float* __restrict__ Whh, u16* __restrict__ Bf)
{
    int chunk = blockIdx.x * 256 + threadIdx.x;  // 2048*512/8 = 131072
    int lane = chunk & 63, s_ = (chunk >> 6) & 3, kt = (chunk >> 8) & 15, grp = chunk >> 12;
    int srow = (s_ << 9) + (grp << 4) + (lane & 15);
    int k0 = (kt << 5) + ((lane >> 4) << 3);
    const float* srcp = Whh + (srow << 9) + k0;
    u16* dst = Bf + (chunk << 3);
#pragma unroll
    for (int j = 0; j < 8; ++j) dst[j] = f2b(srcp[j]);
}

__global__ void prep_misc(const float* __restrict__ Wself, const float* __restrict__ Wneigh,
                          const float* __restrict__ x,
                          u16* __restrict__ WselfT, u16* __restrict__ WneighT,
                          u16* __restrict__ xp)
{
    int idx = blockIdx.x * 256 + threadIdx.x;   // MP*512
    if (idx < 512 * 512) {
        int n = idx >> 9, k = idx & 511;
        WselfT[idx]  = f2b(Wself[(k << 9) + n]);
        WneighT[idx] = f2b(Wneigh[(k << 9) + n]);
    }
    xp[idx] = (idx < NROWS * 512) ? f2b(x[idx]) : (u16)0;
}

extern "C" void kernel_launch(void* const* d_in, const int* in_sizes, int n_in,
                              void* d_out, int out_size, void* d_ws, size_t ws_size,
                              hipStream_t stream) {
    (void)in_sizes; (void)n_in; (void)out_size; (void)ws_size;
    const float* x     = (const float*)d_in[0];
    const int*   src   = (const int*)d_in[1];
    const float* Wih1  = (const float*)d_in[2];
    const float* Whh1  = (const float*)d_in[3];
    const float* bih1  = (const float*)d_in[4];
    const float* bhh1  = (const float*)d_in[5];
    const float* Wself = (const float*)d_in[6];
    const float* Wneigh= (const float*)d_in[7];
    const float* bvec  = (const float*)d_in[8];
    const float* Wih2  = (const float*)d_in[9];
    const float* Whh2  = (const float*)d_in[10];
    const float* bih2  = (const float*)d_in[11];
    const float* bhh2  = (const float*)d_in[12];
    float* out = (float*)d_out;

    char* w = (char*)d_ws;
    auto alloc = [&](size_t bytes) { char* p = w; w += (bytes + 255) & ~(size_t)255; return p; };
    u16*   xp     = (u16*)  alloc((size_t)MP * 512 * 2);
    u16*   ha     = (u16*)  alloc((size_t)MP * 512 * 2);   // stage-1 final h (bf16)
    u16*   hs     = (u16*)  alloc((size_t)MP * 512 * 2);   // sage output (bf16)
    half4* gateX  = (half4*)alloc((size_t)NROWS * 512 * 8);
    u16*   Wih1p  = (u16*)  alloc((size_t)GN * 512 * 2);
    u16*   Wih2p  = (u16*)  alloc((size_t)GN * 512 * 2);
    u16*   Bf1    = (u16*)  alloc((size_t)GN * 512 * 2);
    u16*   Bf2    = (u16*)  alloc((size_t)GN * 512 * 2);
    u16*   WselfT = (u16*)  alloc((size_t)512 * 512 * 2);
    u16*   WneighT= (u16*)  alloc((size_t)512 * 512 * 2);
    float* biasv1 = (float*)alloc(GN * 4);
    float* biasv2 = (float*)alloc(GN * 4);

    dim3 blk(256);
    prep_lstm_w<<<4096, blk, 0, stream>>>(Wih1, bih1, bhh1, Wih1p, biasv1);
    prep_lstm_w<<<4096, blk, 0, stream>>>(Wih2, bih2, bhh2, Wih2p, biasv2);
    prep_whh_frag<<<512, blk, 0, stream>>>(Whh1, Bf1);
    prep_whh_frag<<<512, blk, 0, stream>>>(Whh2, Bf2);
    prep_misc<<<20224, blk, 0, stream>>>(Wself, Wneigh, x, WselfT, WneighT, xp);

    // Stage 1
    gemm_gatex<<<dim3(MT, 16), blk, 0, stream>>>(xp, Wih1p, (const float4v*)biasv1, gateX);
    lstm_scan<<<NBLK, 512, 0, stream>>>(Bf1, gateX, src, ha, nullptr);
    // SAGE combine
    gemm_sage<<<dim3(MT, 4), blk, 0, stream>>>(xp, WselfT, ha, WneighT, bvec, hs);
    // Stage 2
    gemm_gatex<<<dim3(MT, 16), blk, 0, stream>>>(hs, Wih2p, (const float4v*)biasv2, gateX);
    lstm_scan<<<NBLK, 512, 0, stream>>>(Bf2, gateX, src, nullptr, out);
}